// Round 2
// baseline (5405.886 us; speedup 1.0000x reference)
//
#include <hip/hip_runtime.h>
#include <hip/hip_bf16.h>

#define BB 16384
#define NN 54
#define TT 80
#define HH 48
#define PH 80
#define SHH 32
#define AA 397
#define EPSF 1e-5f

typedef __hip_bfloat16 bf16;

__device__ __forceinline__ float tof(float x){ return x; }
__device__ __forceinline__ float tof(bf16 x){ return __bfloat162float(x); }
__device__ __forceinline__ void stor(float* p, float v){ *p = v; }
__device__ __forceinline__ void stor(bf16* p, float v){ *p = __float2bfloat16(v); }

// mish(x) = x * tanh(softplus(x)) = x * w/(w+2), w = e*(2+e), e = exp(x)
__device__ __forceinline__ float mishf(float x){
    float e = __expf(fminf(x, 15.f));
    float w = e * (2.f + e);
    return x * w / (w + 2.f);
}

struct P30 { const void* a[30]; };

// Runtime dtype probe: bf16 data has sane exponents at EVEN element indices;
// fp32 data read as bf16 has uniform-random exponents there (low mantissa bits).
__global__ void k_detect(const unsigned short* tr, int* flag){
    if (threadIdx.x == 0 && blockIdx.x == 0){
        int good = 0;
        for (int i = 0; i < 1024; i += 2){
            int e = (tr[i] >> 7) & 0xFF;
            if (e >= 117 && e <= 137) good++;
        }
        *flag = (good > 256) ? 1 : 0;   // 1 = bf16, 0 = float32
    }
}

// ---------------- K1: trunk layernorm + gfc1 ----------------
template<typename T>
__device__ __forceinline__ void tn_h_body(
        const T* __restrict__ trunk, const T* __restrict__ lw, const T* __restrict__ lb,
        const T* __restrict__ w1, const T* __restrict__ b1,
        float* __restrict__ tn_out, float* __restrict__ h_out){
    __shared__ float s_tn[4][TT];
    int wave = threadIdx.x >> 6, lane = threadIdx.x & 63;
    int row  = blockIdx.x * 4 + wave;
    const T* tr = trunk + row * TT;
    float x0 = (lane < TT)      ? tof(tr[lane])      : 0.f;
    float x1 = (lane + 64 < TT) ? tof(tr[lane + 64]) : 0.f;
    float s = x0 + x1;
    for (int m = 32; m; m >>= 1) s += __shfl_xor(s, m, 64);
    float mu = s / TT;
    float d0 = (lane < TT)      ? (x0 - mu) : 0.f;
    float d1 = (lane + 64 < TT) ? (x1 - mu) : 0.f;
    float v = d0*d0 + d1*d1;
    for (int m = 32; m; m >>= 1) v += __shfl_xor(v, m, 64);
    float rstd = rsqrtf(v / TT + EPSF);
    if (lane < TT){
        float t = d0 * rstd * tof(lw[lane]) + tof(lb[lane]);
        s_tn[wave][lane] = t;
        tn_out[row*TT + lane] = t;
    }
    if (lane + 64 < TT){
        int i = lane + 64;
        float t = d1 * rstd * tof(lw[i]) + tof(lb[i]);
        s_tn[wave][i] = t;
        tn_out[row*TT + i] = t;
    }
    __syncthreads();
    for (int j = lane; j < PH; j += 64){
        float acc = tof(b1[j]);
        const T* wr = w1 + j*TT;
        #pragma unroll 8
        for (int k = 0; k < TT; ++k) acc += s_tn[wave][k] * tof(wr[k]);
        h_out[row*PH + j] = acc;
    }
}

__global__ __launch_bounds__(256) void k_tn_h(P30 p, float* tn_out, float* h_out,
                                              const int* __restrict__ flag){
    if (*flag)
        tn_h_body<bf16>((const bf16*)p.a[0], (const bf16*)p.a[4], (const bf16*)p.a[5],
                        (const bf16*)p.a[8], (const bf16*)p.a[9], tn_out, h_out);
    else
        tn_h_body<float>((const float*)p.a[0], (const float*)p.a[4], (const float*)p.a[5],
                         (const float*)p.a[8], (const float*)p.a[9], tn_out, h_out);
}

// ---------------- K2: batchnorm stats over B ----------------
template<typename T>
__device__ __forceinline__ void bnstats_body(
        const float* __restrict__ h, const T* __restrict__ bw, const T* __restrict__ bb,
        float* __restrict__ scale, float* __restrict__ shift){
    __shared__ float ss[256], sq[256];
    int f = blockIdx.x;
    float s = 0.f, q = 0.f;
    for (int b = threadIdx.x; b < BB; b += 256){
        float x = h[b*PH + f];
        s += x; q += x*x;
    }
    ss[threadIdx.x] = s; sq[threadIdx.x] = q;
    __syncthreads();
    for (int m = 128; m; m >>= 1){
        if ((int)threadIdx.x < m){
            ss[threadIdx.x] += ss[threadIdx.x + m];
            sq[threadIdx.x] += sq[threadIdx.x + m];
        }
        __syncthreads();
    }
    if (threadIdx.x == 0){
        float mu  = ss[0] / BB;
        float var = sq[0] / BB - mu*mu;
        float sc  = rsqrtf(var + EPSF) * tof(bw[f]);
        scale[f] = sc;
        shift[f] = tof(bb[f]) - mu * sc;
    }
}

__global__ __launch_bounds__(256) void k_bnstats(P30 p, const float* h,
                                                 float* scale, float* shift,
                                                 const int* __restrict__ flag){
    if (*flag) bnstats_body<bf16>(h, (const bf16*)p.a[10], (const bf16*)p.a[11], scale, shift);
    else       bnstats_body<float>(h, (const float*)p.a[10], (const float*)p.a[11], scale, shift);
}

// ---------------- K3: global head (122 surviving cols) ----------------
template<typename T>
__device__ __forceinline__ void global_body(
        const float* __restrict__ h, const float* __restrict__ scale,
        const float* __restrict__ shift, const T* __restrict__ w2,
        const T* __restrict__ b2v, T* __restrict__ out){
    __shared__ float m[PH];
    int row = blockIdx.x;
    int t = threadIdx.x;
    if (t < PH) m[t] = mishf(h[row*PH + t] * scale[t] + shift[t]);
    __syncthreads();
    if (t < 122){
        int c = (t < 5) ? t : (280 + t - 5);
        const T* wr = w2 + c*PH;
        float acc = tof(b2v[c]);
        #pragma unroll 8
        for (int k = 0; k < PH; ++k) acc += m[k] * tof(wr[k]);
        stor(out + (long long)row*AA + c, acc);
    }
}

__global__ __launch_bounds__(128) void k_global(P30 p, const float* h,
                                                const float* scale, const float* shift,
                                                void* out, const int* __restrict__ flag){
    if (*flag) global_body<bf16>(h, scale, shift, (const bf16*)p.a[12], (const bf16*)p.a[13], (bf16*)out);
    else       global_body<float>(h, scale, shift, (const float*)p.a[12], (const float*)p.a[13], (float*)out);
}

// ---------------- K4: node LN + all small heads ----------------
template<typename T>
__device__ __forceinline__ void heads_body(
    const T* __restrict__ node_emb, const int* __restrict__ road_pairs,
    const int* __restrict__ tile_nodes,
    const T* __restrict__ lnw, const T* __restrict__ lnb,
    const float* __restrict__ tn_g,
    const T* __restrict__ sett1_w, const T* __restrict__ sett1_b,
    const T* __restrict__ sett2_w, const T* __restrict__ sett2_b,
    const T* __restrict__ city1_w, const T* __restrict__ city1_b,
    const T* __restrict__ city2_w, const T* __restrict__ city2_b,
    const T* __restrict__ road1_w, const T* __restrict__ road1_b,
    const T* __restrict__ road2_w, const T* __restrict__ road2_b,
    const T* __restrict__ rob1_w,  const T* __restrict__ rob1_b,
    const T* __restrict__ rob2_w,  const T* __restrict__ rob2_b,
    T* __restrict__ out){
    __shared__ float s_tn[TT];
    __shared__ float s_nn[NN*HH];
    __shared__ float s_tile[19*HH];
    int row  = blockIdx.x;
    int tid  = threadIdx.x;
    int wave = tid >> 6, lane = tid & 63;

    if (tid < TT) s_tn[tid] = tn_g[row*TT + tid];

    for (int n = wave; n < NN; n += 4){
        const T* ne = node_emb + (row*NN + n)*HH;
        float x = (lane < HH) ? tof(ne[lane]) : 0.f;
        float s = x, q = x*x;
        for (int m2 = 32; m2; m2 >>= 1){
            s += __shfl_xor(s, m2, 64);
            q += __shfl_xor(q, m2, 64);
        }
        float mu   = s / HH;
        float var  = q / HH - mu*mu;
        float rstd = rsqrtf(fmaxf(var, 0.f) + EPSF);
        if (lane < HH)
            s_nn[n*HH + lane] = (x - mu)*rstd*tof(lnw[lane]) + tof(lnb[lane]);
    }
    __syncthreads();

    for (int i = tid; i < 19*HH; i += 256){
        int tI = i / HH, c = i % HH;
        float s = 0.f;
        #pragma unroll
        for (int j = 0; j < 6; ++j){
            int n = tile_nodes[tI*6 + j];
            s += s_nn[n*HH + c];
        }
        s_tile[i] = s * (1.f/6.f);
    }
    __syncthreads();

    int half = tid >> 5, hl = tid & 31;
    T* orow = out + (long long)row*AA;
    for (int task = half; task < 199; task += 8){
        if (task < 108){
            bool city = (task >= 54);
            int n = city ? task - 54 : task;
            const T* w1  = city ? city1_w : sett1_w;
            const T* b1  = city ? city1_b : sett1_b;
            const T* w2  = city ? city2_w : sett2_w;
            const T* b2v = city ? city2_b : sett2_b;
            const T* wr = w1 + hl*(TT+HH);
            float acc = tof(b1[hl]);
            #pragma unroll 8
            for (int k = 0; k < TT; ++k) acc += s_tn[k] * tof(wr[k]);
            const float* nv = s_nn + n*HH;
            #pragma unroll 8
            for (int k = 0; k < HH; ++k) acc += nv[k] * tof(wr[TT+k]);
            float val = mishf(acc) * tof(w2[hl]);
            for (int m2 = 16; m2; m2 >>= 1) val += __shfl_xor(val, m2, 64);
            if (hl == 0) stor(orow + (city ? 59 : 5) + n, val + tof(b2v[0]));
        } else if (task < 180){
            int r = task - 108;
            int srcn = road_pairs[r*2], dstn = road_pairs[r*2+1];
            const T* wr = road1_w + hl*(TT+2*HH);
            float acc = tof(road1_b[hl]);
            #pragma unroll 8
            for (int k = 0; k < TT; ++k) acc += s_tn[k] * tof(wr[k]);
            const float* sv = s_nn + srcn*HH;
            #pragma unroll 8
            for (int k = 0; k < HH; ++k) acc += sv[k] * tof(wr[TT+k]);
            const float* dv = s_nn + dstn*HH;
            #pragma unroll 8
            for (int k = 0; k < HH; ++k) acc += dv[k] * tof(wr[TT+HH+k]);
            float val = mishf(acc) * tof(road2_w[hl]);
            for (int m2 = 16; m2; m2 >>= 1) val += __shfl_xor(val, m2, 64);
            if (hl == 0) stor(orow + 113 + r, val + tof(road2_b[0]));
        } else {
            int ti = task - 180;
            const T* wr = rob1_w + hl*(TT+HH);
            float acc = tof(rob1_b[hl]);
            #pragma unroll 8
            for (int k = 0; k < TT; ++k) acc += s_tn[k] * tof(wr[k]);
            const float* tv = s_tile + ti*HH;
            #pragma unroll 8
            for (int k = 0; k < HH; ++k) acc += tv[k] * tof(wr[TT+k]);
            float hid = mishf(acc);
            #pragma unroll
            for (int k = 0; k < 5; ++k){
                float val = hid * tof(rob2_w[k*SHH + hl]);
                for (int m2 = 16; m2; m2 >>= 1) val += __shfl_xor(val, m2, 64);
                if (hl == 0) stor(orow + 185 + ti*5 + k, val + tof(rob2_b[k]));
            }
        }
    }
}

__global__ __launch_bounds__(256) void k_heads(P30 p, const float* tn_g, void* out,
                                               const int* __restrict__ flag){
    if (*flag)
        heads_body<bf16>((const bf16*)p.a[1], (const int*)p.a[2], (const int*)p.a[3],
            (const bf16*)p.a[6], (const bf16*)p.a[7], tn_g,
            (const bf16*)p.a[14], (const bf16*)p.a[15], (const bf16*)p.a[16], (const bf16*)p.a[17],
            (const bf16*)p.a[18], (const bf16*)p.a[19], (const bf16*)p.a[20], (const bf16*)p.a[21],
            (const bf16*)p.a[22], (const bf16*)p.a[23], (const bf16*)p.a[24], (const bf16*)p.a[25],
            (const bf16*)p.a[26], (const bf16*)p.a[27], (const bf16*)p.a[28], (const bf16*)p.a[29],
            (bf16*)out);
    else
        heads_body<float>((const float*)p.a[1], (const int*)p.a[2], (const int*)p.a[3],
            (const float*)p.a[6], (const float*)p.a[7], tn_g,
            (const float*)p.a[14], (const float*)p.a[15], (const float*)p.a[16], (const float*)p.a[17],
            (const float*)p.a[18], (const float*)p.a[19], (const float*)p.a[20], (const float*)p.a[21],
            (const float*)p.a[22], (const float*)p.a[23], (const float*)p.a[24], (const float*)p.a[25],
            (const float*)p.a[26], (const float*)p.a[27], (const float*)p.a[28], (const float*)p.a[29],
            (float*)out);
}

extern "C" void kernel_launch(void* const* d_in, const int* in_sizes, int n_in,
                              void* d_out, int out_size, void* d_ws, size_t ws_size,
                              hipStream_t stream){
    P30 p;
    for (int i = 0; i < 30; ++i) p.a[i] = d_in[i];

    int*   flag  = (int*)d_ws;
    float* h     = (float*)((char*)d_ws + 256);     // B*PH floats
    float* tn    = h + (size_t)BB*PH;               // B*T floats
    float* scale = tn + (size_t)BB*TT;              // PH
    float* shift = scale + PH;                      // PH

    k_detect<<<1, 64, 0, stream>>>((const unsigned short*)d_in[0], flag);
    k_tn_h<<<BB/4, 256, 0, stream>>>(p, tn, h, flag);
    k_bnstats<<<PH, 256, 0, stream>>>(p, h, scale, shift, flag);
    k_global<<<BB, 128, 0, stream>>>(p, h, scale, shift, d_out, flag);
    k_heads<<<BB, 256, 0, stream>>>(p, tn, d_out, flag);
}